// Round 2
// baseline (1624.410 us; speedup 1.0000x reference)
//
#include <hip/hip_runtime.h>
#include <stdint.h>

typedef __attribute__((ext_vector_type(4))) float f32x4;
typedef __attribute__((ext_vector_type(8))) _Float16 f16x8;

static __device__ __forceinline__ unsigned short f2h(float f) {
    union { _Float16 h; unsigned short u; } v;
    v.h = (_Float16)f;                      // v_cvt_f16_f32, RNE
    return v.u;
}
static __device__ __forceinline__ float h2f_lo(unsigned int u) {
    union { unsigned short s; _Float16 h; } v; v.s = (unsigned short)(u & 0xffffu);
    return (float)v.h;
}
static __device__ __forceinline__ float h2f_hi(unsigned int u) {
    union { unsigned short s; _Float16 h; } v; v.s = (unsigned short)(u >> 16);
    return (float)v.h;
}
static __device__ __forceinline__ f16x8 as_f16x8(uint4 v) {
    union { uint4 u; f16x8 s; } x; x.u = v; return x.s;
}
static __device__ __forceinline__ float sigmoid_fast(float x) {
    return __builtin_amdgcn_rcpf(1.0f + __builtin_amdgcn_exp2f(-1.4426950408889634f * x));
}
static __device__ __forceinline__ float tanh_fast(float x) {
    return 1.0f - 2.0f * __builtin_amdgcn_rcpf(1.0f + __builtin_amdgcn_exp2f(2.8853900817779268f * x));
}
// barrier that waits only LDS (lgkmcnt(0)), NOT vmcnt — global stores keep retiring async,
// cross-step weight prefetch stays in flight (CK block_sync_lds idiom).
static __device__ __forceinline__ void lds_barrier() {
    __builtin_amdgcn_s_waitcnt(0xc07f);
    __builtin_amdgcn_s_barrier();
}

// ---------- fused fp32 -> fp16 conversion for all 6 tensors (1 dispatch) ----------
// float4-index regions (compile-time): h 131072 | c 131072 | iWh 65536 | iWc 65536 | Wih 131072 | Whh 65536
__global__ __launch_bounds__(256) void convert_all(
    const float* __restrict__ h, const float* __restrict__ c,
    const float* __restrict__ iWh, const float* __restrict__ iWc,
    const float* __restrict__ Wih, const float* __restrict__ Whh,
    unsigned short* __restrict__ hc_h, unsigned short* __restrict__ iWh_h,
    unsigned short* __restrict__ iWc_h, unsigned short* __restrict__ Wih_h,
    unsigned short* __restrict__ Whh_h) {
    int i = blockIdx.x * 256 + threadIdx.x;      // float4 index, total 589824
    const float* src; unsigned short* dst;
    if (i < 131072) {            // h -> hc[:, 0:512]
        int base = i * 4, r = base >> 9, cc = base & 511;
        src = h + base; dst = hc_h + r * 1024 + cc;
    } else if (i < 262144) {     // c -> hc[:, 512:1024]
        int j = i - 131072; int base = j * 4, r = base >> 9, cc = base & 511;
        src = c + base; dst = hc_h + r * 1024 + 512 + cc;
    } else if (i < 327680) { int j = i - 262144; src = iWh + j * 4; dst = iWh_h + j * 4; }
    else if (i < 393216)   { int j = i - 327680; src = iWc + j * 4; dst = iWc_h + j * 4; }
    else if (i < 524288)   { int j = i - 393216; src = Wih + j * 4; dst = Wih_h + j * 4; }
    else                   { int j = i - 524288; src = Whh + j * 4; dst = Whh_h + j * 4; }
    float4 v = *(const float4*)src;
    dst[0] = f2h(v.x); dst[1] = f2h(v.y); dst[2] = f2h(v.z); dst[3] = f2h(v.w);
}

// ---------- generic C[M,N] = A[M,lda] @ W[N,ldw(:K)]^T + bias (+ELU), fp16 in / fp32 out ----
// bias_row: bias indexed by output ROW instead of column (used for the transposed x-proj).
__global__ __launch_bounds__(256) void gemm_bt(
    const unsigned short* __restrict__ A, const unsigned short* __restrict__ W,
    float* __restrict__ C, const float* __restrict__ b1, const float* __restrict__ b2,
    int K, int lda, int ldw, int N, int do_elu, int bias_row) {
    __shared__ unsigned short As[64][40];
    __shared__ unsigned short Bs[64][40];
    int tid = threadIdx.x;
    int lane = tid & 63, wv = tid >> 6;
    int q = lane >> 4, l15 = lane & 15;
    int Mbase = blockIdx.x * 64, Nbase = blockIdx.y * 64;
    int ldrow = tid >> 2, seg = tid & 3;
    const unsigned short* Ap = A + (size_t)(Mbase + ldrow) * lda + seg * 8;
    const unsigned short* Wp = W + (size_t)(Nbase + ldrow) * ldw + seg * 8;
    f32x4 acc[4] = {};
    for (int k0 = 0; k0 < K; k0 += 32) {
        uint4 av = *(const uint4*)(Ap + k0);
        uint4 wvv = *(const uint4*)(Wp + k0);
        __syncthreads();
        *(uint4*)(&As[ldrow][seg * 8]) = av;
        *(uint4*)(&Bs[ldrow][seg * 8]) = wvv;
        __syncthreads();
        f16x8 af = *(const f16x8*)(&As[wv * 16 + l15][q * 8]);
#pragma unroll
        for (int nt = 0; nt < 4; nt++) {
            f16x8 bf = *(const f16x8*)(&Bs[nt * 16 + l15][q * 8]);
            acc[nt] = __builtin_amdgcn_mfma_f32_16x16x32_f16(af, bf, acc[nt], 0, 0, 0);
        }
    }
#pragma unroll
    for (int nt = 0; nt < 4; nt++) {
        int col = Nbase + nt * 16 + l15;
        float bcol = bias_row ? 0.0f : (b1[col] + (b2 ? b2[col] : 0.0f));
#pragma unroll
        for (int r = 0; r < 4; r++) {
            int row = Mbase + wv * 16 + q * 4 + r;
            float bias = bias_row ? (b1[row] + (b2 ? b2[row] : 0.0f)) : bcol;
            float v = acc[nt][r] + bias;
            if (do_elu) v = v > 0.0f ? v : (__builtin_amdgcn_exp2f(1.4426950408889634f * v) - 1.0f);
            C[(size_t)row * N + col] = v;
        }
    }
}

// ---------- fused init-state GEMMs (h0 and c0 via blockIdx.z), K=1024, N=256, ELU ----------
__global__ __launch_bounds__(256) void gemm_init(
    const unsigned short* __restrict__ A,
    const unsigned short* __restrict__ W0, const unsigned short* __restrict__ W1,
    float* __restrict__ C0, float* __restrict__ C1,
    const float* __restrict__ bias0, const float* __restrict__ bias1) {
    const unsigned short* W = blockIdx.z ? W1 : W0;
    float* C = blockIdx.z ? C1 : C0;
    const float* bias = blockIdx.z ? bias1 : bias0;
    __shared__ unsigned short As[64][40];
    __shared__ unsigned short Bs[64][40];
    int tid = threadIdx.x;
    int lane = tid & 63, wv = tid >> 6;
    int q = lane >> 4, l15 = lane & 15;
    int Mbase = blockIdx.x * 64, Nbase = blockIdx.y * 64;
    int ldrow = tid >> 2, seg = tid & 3;
    const unsigned short* Ap = A + (size_t)(Mbase + ldrow) * 1024 + seg * 8;
    const unsigned short* Wp = W + (size_t)(Nbase + ldrow) * 1024 + seg * 8;
    f32x4 acc[4] = {};
    for (int k0 = 0; k0 < 1024; k0 += 32) {
        uint4 av = *(const uint4*)(Ap + k0);
        uint4 wvv = *(const uint4*)(Wp + k0);
        __syncthreads();
        *(uint4*)(&As[ldrow][seg * 8]) = av;
        *(uint4*)(&Bs[ldrow][seg * 8]) = wvv;
        __syncthreads();
        f16x8 af = *(const f16x8*)(&As[wv * 16 + l15][q * 8]);
#pragma unroll
        for (int nt = 0; nt < 4; nt++) {
            f16x8 bf = *(const f16x8*)(&Bs[nt * 16 + l15][q * 8]);
            acc[nt] = __builtin_amdgcn_mfma_f32_16x16x32_f16(af, bf, acc[nt], 0, 0, 0);
        }
    }
#pragma unroll
    for (int nt = 0; nt < 4; nt++) {
        int col = Nbase + nt * 16 + l15;
        float b = bias[col];
#pragma unroll
        for (int r = 0; r < 4; r++) {
            int row = Mbase + wv * 16 + q * 4 + r;
            float v = acc[nt][r] + b;
            v = v > 0.0f ? v : (__builtin_amdgcn_exp2f(1.4426950408889634f * v) - 1.0f);
            C[(size_t)row * 256 + col] = v;
        }
    }
}

// ---------- persistent recurrent kernel: 64 blocks x 1024 thr, 16 rows/block ----------
// wave w owns latent cols [16w,16w+16) for all 4 gates (i,f,g,o in-register elementwise).
// STATIC __shared__ (147968 B) so the compiler KNOWS occupancy = 1 block/CU = 4 waves/SIMD
// and allocates against the full 128-reg/wave budget (two rounds of attribute-only attempts
// left the allocator at 64 arch-VGPRs -> massive per-step scratch traffic).
// Weight residency per wave: kt0-3 in regs (64, expected AGPR side), kt4/kt6 in LDS (128 KB),
// kt5/kt7 streamed from L2 through ONE 16-reg buffer with healthy slack on both legs:
//   consume kt5 (first) -> refill kt7 (consumed ~500 cyc later, after kt0-4,6)
//   consume kt7 (last)  -> refill next-step kt5 (slack = elementwise + barrier)
// x-proj lives as 8 regs of packed f16 (RNE), unpacked at step top — no per-step memory
// loads for acc-init, hence no store->load vmcnt FIFO serialization (round-1's regression:
// acc loads issued after the out-stores stalled every step on store drain).
#define HB_STRIDE 264                    // fp16 elems per h row (padded; 16B-aligned rows)
#define HB_HALF   (16 * HB_STRIDE)      // one h buffer, elems
#define WLDS_OFF  (2 * HB_HALF * 2)     // bytes: 16896
#define LSTM_LDS_BYTES (WLDS_OFF + 16 * 2 * 4 * 1024)   // +131072 = 147968

__global__ __launch_bounds__(1024) __attribute__((amdgpu_waves_per_eu(4, 4)))
void lstm_rec(
    const unsigned short* __restrict__ Whh,   // [1024,256] fp16
    const float* __restrict__ xpT,            // [1024 gatecols, 1024 rows] fp32
    const float* __restrict__ h0,             // [1024,256]
    const float* __restrict__ c0,             // [1024,256]
    const int* __restrict__ seq_len,
    float* __restrict__ out)                  // [1024, T, 256]
{
    __shared__ uint4 smem4[LSTM_LDS_BYTES / 16];        // static: compiler sees 1 block/CU
    unsigned short* hbuf = (unsigned short*)smem4;       // [2][16][HB_STRIDE]
    unsigned char* wlds = (unsigned char*)smem4 + WLDS_OFF; // 16 waves * 2 kt * 4 g * 1024 B
    const int tid = threadIdx.x;
    const int lane = tid & 63, wv = tid >> 6;
    const int q = lane >> 4, l15 = lane & 15;
    const int T = *seq_len;
    const int rowbase = blockIdx.x * 16;

    // global base for this wave's weight fragments: row = g*256 + wv*16 + l15, k = kt*32 + q*8
    const unsigned short* wbase = Whh + ((wv << 4) + l15) * 256 + q * 8;

    // kt0-3 -> registers (16 frags = 64 regs, MFMA-only consumers => AGPR-eligible)
    uint4 wreg[16];
#pragma unroll
    for (int kt = 0; kt < 4; kt++)
#pragma unroll
        for (int g = 0; g < 4; g++)
            wreg[kt * 4 + g] = *(const uint4*)(wbase + (size_t)g * 65536 + kt * 32);

    // kt4, kt6 -> LDS, lane-linear 16B frags (conflict-free b128 pattern)
#pragma unroll
    for (int ki = 0; ki < 2; ki++) {
        const int kt = 4 + 2 * ki;
#pragma unroll
        for (int g = 0; g < 4; g++) {
            uint4 v = *(const uint4*)(wbase + (size_t)g * 65536 + kt * 32);
            *(uint4*)(wlds + (((wv * 2 + ki) * 4 + g) * 64 + lane) * 16) = v;
        }
    }

    float creg[4];
#pragma unroll
    for (int r = 0; r < 4; r++)
        creg[r] = c0[(size_t)(rowbase + q * 4 + r) * 256 + (wv << 4) + l15];

    {   // h0 -> hbuf[0] as fp16
        int e = tid * 4;
        int r = e >> 8, cc = e & 255;
        float4 v = *(const float4*)(h0 + (size_t)(rowbase + r) * 256 + cc);
        unsigned short* d = hbuf + r * HB_STRIDE + cc;
        d[0] = f2h(v.x); d[1] = f2h(v.y); d[2] = f2h(v.z); d[3] = f2h(v.w);
    }

    // x-projection -> 8 regs of packed f16 (RNE per element); unpacked each step (pure VALU)
    unsigned int xph[8];
    {
        const float* xpb = xpT + (size_t)((wv << 4) + l15) * 1024 + rowbase + (q << 2);
#pragma unroll
        for (int g = 0; g < 4; g++) {
            f32x4 v = *(const f32x4*)(xpb + (size_t)g * 262144);
            xph[2 * g]     = (unsigned int)f2h(v[0]) | ((unsigned int)f2h(v[1]) << 16);
            xph[2 * g + 1] = (unsigned int)f2h(v[2]) | ((unsigned int)f2h(v[3]) << 16);
        }
    }

    // stream prefetch kt5 for step 0
    uint4 sbuf[4];
#pragma unroll
    for (int g = 0; g < 4; g++)
        sbuf[g] = *(const uint4*)(wbase + (size_t)g * 65536 + 5 * 32);

    float* outp = out + (size_t)(rowbase + q * 4) * T * 256 + (wv << 4) + l15;

    __syncthreads();

    for (int t = 0; t < T; t++) {
        const unsigned short* hrow = hbuf + (t & 1) * HB_HALF + l15 * HB_STRIDE;
        // acc init from packed-f16 xp (no memory op => no vmcnt wait at step top)
        f32x4 acc[4];
#pragma unroll
        for (int g = 0; g < 4; g++) {
            acc[g][0] = h2f_lo(xph[2 * g]);     acc[g][1] = h2f_hi(xph[2 * g]);
            acc[g][2] = h2f_lo(xph[2 * g + 1]); acc[g][3] = h2f_hi(xph[2 * g + 1]);
        }
        // kt5 FIRST: consume sbuf (loaded >=1/2 step ago), refill with kt7
        {
            f16x8 af = *(const f16x8*)(hrow + 5 * 32 + q * 8);
#pragma unroll
            for (int g = 0; g < 4; g++) {
                acc[g] = __builtin_amdgcn_mfma_f32_16x16x32_f16(af, as_f16x8(sbuf[g]), acc[g], 0, 0, 0);
                sbuf[g] = *(const uint4*)(wbase + (size_t)g * 65536 + 7 * 32);
            }
        }
        // kt0-3: register-resident weights
#pragma unroll
        for (int kt = 0; kt < 4; kt++) {
            f16x8 af = *(const f16x8*)(hrow + kt * 32 + q * 8);
#pragma unroll
            for (int g = 0; g < 4; g++)
                acc[g] = __builtin_amdgcn_mfma_f32_16x16x32_f16(af, as_f16x8(wreg[kt * 4 + g]), acc[g], 0, 0, 0);
        }
        // kt4, kt6: LDS-resident weights (gives the kt7 refill ~500 cycles of cover)
#pragma unroll
        for (int ki = 0; ki < 2; ki++) {
            const int kt = 4 + 2 * ki;
            f16x8 af = *(const f16x8*)(hrow + kt * 32 + q * 8);
#pragma unroll
            for (int g = 0; g < 4; g++) {
                f16x8 bf = *(const f16x8*)(wlds + (((wv * 2 + ki) * 4 + g) * 64 + lane) * 16);
                acc[g] = __builtin_amdgcn_mfma_f32_16x16x32_f16(af, bf, acc[g], 0, 0, 0);
            }
        }
        // kt7 LAST: consume sbuf, refill with NEXT step's kt5 (stays in flight across barrier)
        {
            f16x8 af = *(const f16x8*)(hrow + 7 * 32 + q * 8);
#pragma unroll
            for (int g = 0; g < 4; g++) {
                acc[g] = __builtin_amdgcn_mfma_f32_16x16x32_f16(af, as_f16x8(sbuf[g]), acc[g], 0, 0, 0);
                sbuf[g] = *(const uint4*)(wbase + (size_t)g * 65536 + 5 * 32);
            }
        }
        // elementwise (in-register); ds_writes first, global stores LAST (FIFO hygiene:
        // no loop load is ever issued after a store)
        unsigned short* hn = hbuf + ((t + 1) & 1) * HB_HALF;
#pragma unroll
        for (int r = 0; r < 4; r++) {
            float ig = sigmoid_fast(acc[0][r]);
            float fg = sigmoid_fast(acc[1][r]);
            float gg = tanh_fast(acc[2][r]);
            float og = sigmoid_fast(acc[3][r]);
            float cn = fg * creg[r] + ig * gg;
            creg[r] = cn;
            float hv = og * tanh_fast(cn);
            hn[(q * 4 + r) * HB_STRIDE + (wv << 4) + l15] = f2h(hv);
            outp[(size_t)r * T * 256] = hv;
        }
        outp += 256;
        lds_barrier();
    }
}

extern "C" void kernel_launch(void* const* d_in, const int* in_sizes, int n_in,
                              void* d_out, int out_size, void* d_ws, size_t ws_size,
                              hipStream_t stream) {
    const float* h   = (const float*)d_in[0];
    const float* c   = (const float*)d_in[1];
    const int*   seqp= (const int*)d_in[2];
    const float* iWh = (const float*)d_in[3];
    const float* ibh = (const float*)d_in[4];
    const float* iWc = (const float*)d_in[5];
    const float* ibc = (const float*)d_in[6];
    const float* Wih = (const float*)d_in[7];
    const float* Whh = (const float*)d_in[8];
    const float* bih = (const float*)d_in[9];
    const float* bhh = (const float*)d_in[10];
    float* out = (float*)d_out;
    unsigned char* ws = (unsigned char*)d_ws;

    // workspace layout (16B-aligned)
    unsigned short* hc_h  = (unsigned short*)(ws + 0);        // [1024,1024] fp16 = 2 MB
    unsigned short* iWh_h = (unsigned short*)(ws + 2097152);  // [256,1024]
    unsigned short* iWc_h = (unsigned short*)(ws + 2621440);  // [256,1024]
    unsigned short* Wih_h = (unsigned short*)(ws + 3145728);  // [1024,512]
    unsigned short* Whh_h = (unsigned short*)(ws + 4194304);  // [1024,256]
    float* h0  = (float*)(ws + 4718592);                       // [1024,256]
    float* c0  = (float*)(ws + 5767168);                       // [1024,256]
    float* xpT = (float*)(ws + 6815744);                       // [1024 gatecols,1024 rows]

    // fp16 conversions: all 6 tensors in one dispatch
    convert_all<<<2304, 256, 0, stream>>>(h, c, iWh, iWc, Wih, Whh,
                                          hc_h, iWh_h, iWc_h, Wih_h, Whh_h);

    // init states (fused pair) + transposed x_proj:
    // xpT[gatecol, batch] = Wih[gatecol,:] . h[batch,:] + bih[gatecol] + bhh[gatecol]
    gemm_init<<<dim3(16, 4, 2), 256, 0, stream>>>(hc_h, iWh_h, iWc_h, h0, c0, ibh, ibc);
    gemm_bt<<<dim3(16, 16), 256, 0, stream>>>(Wih_h, hc_h, xpT, bih, bhh,
                                              512, 512, 1024, 1024, 0, 1);

    // recurrence (static LDS; no dynamic smem, no hipFuncSetAttribute needed)
    lstm_rec<<<64, 1024, 0, stream>>>(Whh_h, xpT, h0, c0, seqp, out);
}

// Round 3
// 1584.920 us; speedup vs baseline: 1.0249x; 1.0249x over previous
//
#include <hip/hip_runtime.h>
#include <stdint.h>

typedef __attribute__((ext_vector_type(4))) float f32x4;
typedef __attribute__((ext_vector_type(8))) _Float16 f16x8;

static __device__ __forceinline__ unsigned short f2h(float f) {
    union { _Float16 h; unsigned short u; } v;
    v.h = (_Float16)f;                      // v_cvt_f16_f32, RNE
    return v.u;
}
static __device__ __forceinline__ float h2f_lo(unsigned int u) {
    union { unsigned short s; _Float16 h; } v; v.s = (unsigned short)(u & 0xffffu);
    return (float)v.h;
}
static __device__ __forceinline__ float h2f_hi(unsigned int u) {
    union { unsigned short s; _Float16 h; } v; v.s = (unsigned short)(u >> 16);
    return (float)v.h;
}
static __device__ __forceinline__ f16x8 as_f16x8(uint4 v) {
    union { uint4 u; f16x8 s; } x; x.u = v; return x.s;
}
static __device__ __forceinline__ float sigmoid_fast(float x) {
    return __builtin_amdgcn_rcpf(1.0f + __builtin_amdgcn_exp2f(-1.4426950408889634f * x));
}
static __device__ __forceinline__ float tanh_fast(float x) {
    return 1.0f - 2.0f * __builtin_amdgcn_rcpf(1.0f + __builtin_amdgcn_exp2f(2.8853900817779268f * x));
}
// barrier that waits only LDS (lgkmcnt(0)), NOT vmcnt — global stores keep retiring async,
// cross-step weight prefetch stays in flight (CK block_sync_lds idiom).
static __device__ __forceinline__ void lds_barrier() {
    __builtin_amdgcn_s_waitcnt(0xc07f);
    __builtin_amdgcn_s_barrier();
}

// ---------- fused fp32 -> fp16 conversion for all 6 tensors (1 dispatch) ----------
__global__ __launch_bounds__(256) void convert_all(
    const float* __restrict__ h, const float* __restrict__ c,
    const float* __restrict__ iWh, const float* __restrict__ iWc,
    const float* __restrict__ Wih, const float* __restrict__ Whh,
    unsigned short* __restrict__ hc_h, unsigned short* __restrict__ iWh_h,
    unsigned short* __restrict__ iWc_h, unsigned short* __restrict__ Wih_h,
    unsigned short* __restrict__ Whh_h) {
    int i = blockIdx.x * 256 + threadIdx.x;      // float4 index, total 589824
    const float* src; unsigned short* dst;
    if (i < 131072) {            // h -> hc[:, 0:512]
        int base = i * 4, r = base >> 9, cc = base & 511;
        src = h + base; dst = hc_h + r * 1024 + cc;
    } else if (i < 262144) {     // c -> hc[:, 512:1024]
        int j = i - 131072; int base = j * 4, r = base >> 9, cc = base & 511;
        src = c + base; dst = hc_h + r * 1024 + 512 + cc;
    } else if (i < 327680) { int j = i - 262144; src = iWh + j * 4; dst = iWh_h + j * 4; }
    else if (i < 393216)   { int j = i - 327680; src = iWc + j * 4; dst = iWc_h + j * 4; }
    else if (i < 524288)   { int j = i - 393216; src = Wih + j * 4; dst = Wih_h + j * 4; }
    else                   { int j = i - 524288; src = Whh + j * 4; dst = Whh_h + j * 4; }
    float4 v = *(const float4*)src;
    dst[0] = f2h(v.x); dst[1] = f2h(v.y); dst[2] = f2h(v.z); dst[3] = f2h(v.w);
}

// ---------- generic C[M,N] = A[M,lda] @ W[N,ldw(:K)]^T + bias (+ELU), fp16 in / fp32 out ----
// bias_row: bias indexed by output ROW instead of column (used for the transposed x-proj).
__global__ __launch_bounds__(256) void gemm_bt(
    const unsigned short* __restrict__ A, const unsigned short* __restrict__ W,
    float* __restrict__ C, const float* __restrict__ b1, const float* __restrict__ b2,
    int K, int lda, int ldw, int N, int do_elu, int bias_row) {
    __shared__ unsigned short As[64][40];
    __shared__ unsigned short Bs[64][40];
    int tid = threadIdx.x;
    int lane = tid & 63, wv = tid >> 6;
    int q = lane >> 4, l15 = lane & 15;
    int Mbase = blockIdx.x * 64, Nbase = blockIdx.y * 64;
    int ldrow = tid >> 2, seg = tid & 3;
    const unsigned short* Ap = A + (size_t)(Mbase + ldrow) * lda + seg * 8;
    const unsigned short* Wp = W + (size_t)(Nbase + ldrow) * ldw + seg * 8;
    f32x4 acc[4] = {};
    for (int k0 = 0; k0 < K; k0 += 32) {
        uint4 av = *(const uint4*)(Ap + k0);
        uint4 wvv = *(const uint4*)(Wp + k0);
        __syncthreads();
        *(uint4*)(&As[ldrow][seg * 8]) = av;
        *(uint4*)(&Bs[ldrow][seg * 8]) = wvv;
        __syncthreads();
        f16x8 af = *(const f16x8*)(&As[wv * 16 + l15][q * 8]);
#pragma unroll
        for (int nt = 0; nt < 4; nt++) {
            f16x8 bf = *(const f16x8*)(&Bs[nt * 16 + l15][q * 8]);
            acc[nt] = __builtin_amdgcn_mfma_f32_16x16x32_f16(af, bf, acc[nt], 0, 0, 0);
        }
    }
#pragma unroll
    for (int nt = 0; nt < 4; nt++) {
        int col = Nbase + nt * 16 + l15;
        float bcol = bias_row ? 0.0f : (b1[col] + (b2 ? b2[col] : 0.0f));
#pragma unroll
        for (int r = 0; r < 4; r++) {
            int row = Mbase + wv * 16 + q * 4 + r;
            float bias = bias_row ? (b1[row] + (b2 ? b2[row] : 0.0f)) : bcol;
            float v = acc[nt][r] + bias;
            if (do_elu) v = v > 0.0f ? v : (__builtin_amdgcn_exp2f(1.4426950408889634f * v) - 1.0f);
            C[(size_t)row * N + col] = v;
        }
    }
}

// ---------- fused init-state GEMMs (h0 and c0 via blockIdx.z), K=1024, N=256, ELU ----------
__global__ __launch_bounds__(256) void gemm_init(
    const unsigned short* __restrict__ A,
    const unsigned short* __restrict__ W0, const unsigned short* __restrict__ W1,
    float* __restrict__ C0, float* __restrict__ C1,
    const float* __restrict__ bias0, const float* __restrict__ bias1) {
    const unsigned short* W = blockIdx.z ? W1 : W0;
    float* C = blockIdx.z ? C1 : C0;
    const float* bias = blockIdx.z ? bias1 : bias0;
    __shared__ unsigned short As[64][40];
    __shared__ unsigned short Bs[64][40];
    int tid = threadIdx.x;
    int lane = tid & 63, wv = tid >> 6;
    int q = lane >> 4, l15 = lane & 15;
    int Mbase = blockIdx.x * 64, Nbase = blockIdx.y * 64;
    int ldrow = tid >> 2, seg = tid & 3;
    const unsigned short* Ap = A + (size_t)(Mbase + ldrow) * 1024 + seg * 8;
    const unsigned short* Wp = W + (size_t)(Nbase + ldrow) * 1024 + seg * 8;
    f32x4 acc[4] = {};
    for (int k0 = 0; k0 < 1024; k0 += 32) {
        uint4 av = *(const uint4*)(Ap + k0);
        uint4 wvv = *(const uint4*)(Wp + k0);
        __syncthreads();
        *(uint4*)(&As[ldrow][seg * 8]) = av;
        *(uint4*)(&Bs[ldrow][seg * 8]) = wvv;
        __syncthreads();
        f16x8 af = *(const f16x8*)(&As[wv * 16 + l15][q * 8]);
#pragma unroll
        for (int nt = 0; nt < 4; nt++) {
            f16x8 bf = *(const f16x8*)(&Bs[nt * 16 + l15][q * 8]);
            acc[nt] = __builtin_amdgcn_mfma_f32_16x16x32_f16(af, bf, acc[nt], 0, 0, 0);
        }
    }
#pragma unroll
    for (int nt = 0; nt < 4; nt++) {
        int col = Nbase + nt * 16 + l15;
        float b = bias[col];
#pragma unroll
        for (int r = 0; r < 4; r++) {
            int row = Mbase + wv * 16 + q * 4 + r;
            float v = acc[nt][r] + b;
            v = v > 0.0f ? v : (__builtin_amdgcn_exp2f(1.4426950408889634f * v) - 1.0f);
            C[(size_t)row * 256 + col] = v;
        }
    }
}

// ---------- persistent recurrent kernel: 64 blocks x 1024 thr, 16 rows/block ----------
// wave w owns latent cols [16w,16w+16) for all 4 gates (i,f,g,o in-register elementwise).
// RESIDENCY = round-0 split (the only one that fit the unified 128-reg/wave budget):
//   kt0-1 in regs (8 frags -> AGPR side with acc), kt2-3 in LDS (128 KB), kt4-7 streamed.
// Rounds 1-2 doubled wreg (+32 regs), overflowed the budget, and regressed (MfmaUtil
// 4.9->3.9, SGPR 32->112). WRITE_SIZE == output bytes in all rounds => never any spill.
// New this round (latency hiding, ~zero net pressure):
//   - xp as 8 packed-f16 regs (was 16 f32) -> -8 arch regs
//   - TWO stream banks, section order kt4,kt5,kt0,kt1,kt2,kt3,kt6,kt7: every streamed
//     consume has >=2 sections (~400-700 cyc) of prefetch lead (round-0 had ~150)
//   - rolling af prefetch: next section's h-fragment ds_read issues before current MFMAs
#define HB_STRIDE 264                    // fp16 elems per h row (padded; 16B-aligned rows)
#define HB_HALF   (16 * HB_STRIDE)      // one h buffer, elems
#define WLDS_OFF  (2 * HB_HALF * 2)     // bytes: 16896
#define LSTM_LDS_BYTES (WLDS_OFF + 16 * 8 * 64 * 16)   // +131072 = 147968

__global__ __launch_bounds__(1024) __attribute__((amdgpu_waves_per_eu(4, 4)))
void lstm_rec(
    const unsigned short* __restrict__ Whh,   // [1024,256] fp16
    const float* __restrict__ xpT,            // [1024 gatecols, 1024 rows] fp32
    const float* __restrict__ h0,             // [1024,256]
    const float* __restrict__ c0,             // [1024,256]
    const int* __restrict__ seq_len,
    float* __restrict__ out)                  // [1024, T, 256]
{
    __shared__ uint4 smem4[LSTM_LDS_BYTES / 16];
    unsigned short* hbuf = (unsigned short*)smem4;          // [2][16][HB_STRIDE]
    unsigned char* wlds = (unsigned char*)smem4 + WLDS_OFF; // 16 waves * 8 frags * 1 KB
    const int tid = threadIdx.x;
    const int lane = tid & 63, wv = tid >> 6;
    const int q = lane >> 4, l15 = lane & 15;
    const int T = *seq_len;
    const int rowbase = blockIdx.x * 16;

    // global base for this wave's weight fragments: row = g*256 + wv*16 + l15, k = kt*32 + q*8
    const unsigned short* wbase = Whh + ((wv << 4) + l15) * 256 + q * 8;

    // kt0-1 -> registers (8 frags = 32 regs, MFMA-only consumers => AGPR-eligible)
    uint4 wreg[8];
#pragma unroll
    for (int kt = 0; kt < 2; kt++)
#pragma unroll
        for (int g = 0; g < 4; g++)
            wreg[kt * 4 + g] = *(const uint4*)(wbase + (size_t)g * 65536 + kt * 32);

    // kt2-3 -> LDS, lane-linear 16B frags (conflict-free b128 pattern)
#pragma unroll
    for (int kt = 2; kt < 4; kt++)
#pragma unroll
        for (int g = 0; g < 4; g++) {
            uint4 v = *(const uint4*)(wbase + (size_t)g * 65536 + kt * 32);
            *(uint4*)(wlds + (((wv * 8) + (kt - 2) * 4 + g) * 64 + lane) * 16) = v;
        }

    float creg[4];
#pragma unroll
    for (int r = 0; r < 4; r++)
        creg[r] = c0[(size_t)(rowbase + q * 4 + r) * 256 + (wv << 4) + l15];

    {   // h0 -> hbuf[0] as fp16
        int e = tid * 4;
        int r = e >> 8, cc = e & 255;
        float4 v = *(const float4*)(h0 + (size_t)(rowbase + r) * 256 + cc);
        unsigned short* d = hbuf + r * HB_STRIDE + cc;
        d[0] = f2h(v.x); d[1] = f2h(v.y); d[2] = f2h(v.z); d[3] = f2h(v.w);
    }

    // x-projection -> 8 regs of packed f16 (RNE); unpacked each step (pure VALU, no vmem)
    unsigned int xph[8];
    {
        const float* xpb = xpT + (size_t)((wv << 4) + l15) * 1024 + rowbase + (q << 2);
#pragma unroll
        for (int g = 0; g < 4; g++) {
            f32x4 v = *(const f32x4*)(xpb + (size_t)g * 262144);
            xph[2 * g]     = (unsigned int)f2h(v[0]) | ((unsigned int)f2h(v[1]) << 16);
            xph[2 * g + 1] = (unsigned int)f2h(v[2]) | ((unsigned int)f2h(v[3]) << 16);
        }
    }

    // stream banks: A holds kt4 (then kt6), B holds kt5 (then kt7)
    uint4 sbufA[4], sbufB[4];
#pragma unroll
    for (int g = 0; g < 4; g++) {
        sbufA[g] = *(const uint4*)(wbase + (size_t)g * 65536 + 4 * 32);
        sbufB[g] = *(const uint4*)(wbase + (size_t)g * 65536 + 5 * 32);
    }

    float* outp = out + (size_t)(rowbase + q * 4) * T * 256 + (wv << 4) + l15;

    __syncthreads();

    for (int t = 0; t < T; t++) {
        const unsigned short* hb = hbuf + (t & 1) * HB_HALF + l15 * HB_STRIDE + q * 8;
        // acc init from packed-f16 xp
        f32x4 acc[4];
#pragma unroll
        for (int g = 0; g < 4; g++) {
            acc[g][0] = h2f_lo(xph[2 * g]);     acc[g][1] = h2f_hi(xph[2 * g]);
            acc[g][2] = h2f_lo(xph[2 * g + 1]); acc[g][3] = h2f_hi(xph[2 * g + 1]);
        }
        f16x8 afc, afn;
        afc = *(const f16x8*)(hb + 4 * 32);               // af for kt4
        // S0: kt4 (bank A, loaded >=1 step ago); refill A <- kt6
        afn = *(const f16x8*)(hb + 5 * 32);
#pragma unroll
        for (int g = 0; g < 4; g++) {
            acc[g] = __builtin_amdgcn_mfma_f32_16x16x32_f16(afc, as_f16x8(sbufA[g]), acc[g], 0, 0, 0);
            sbufA[g] = *(const uint4*)(wbase + (size_t)g * 65536 + 6 * 32);
        }
        afc = afn;
        // S1: kt5 (bank B); refill B <- kt7
        afn = *(const f16x8*)(hb + 0 * 32);
#pragma unroll
        for (int g = 0; g < 4; g++) {
            acc[g] = __builtin_amdgcn_mfma_f32_16x16x32_f16(afc, as_f16x8(sbufB[g]), acc[g], 0, 0, 0);
            sbufB[g] = *(const uint4*)(wbase + (size_t)g * 65536 + 7 * 32);
        }
        afc = afn;
        // S2: kt0 (regs)
        afn = *(const f16x8*)(hb + 1 * 32);
#pragma unroll
        for (int g = 0; g < 4; g++)
            acc[g] = __builtin_amdgcn_mfma_f32_16x16x32_f16(afc, as_f16x8(wreg[g]), acc[g], 0, 0, 0);
        afc = afn;
        // S3: kt1 (regs)
        afn = *(const f16x8*)(hb + 2 * 32);
#pragma unroll
        for (int g = 0; g < 4; g++)
            acc[g] = __builtin_amdgcn_mfma_f32_16x16x32_f16(afc, as_f16x8(wreg[4 + g]), acc[g], 0, 0, 0);
        afc = afn;
        // S4: kt2 (LDS weights)
        afn = *(const f16x8*)(hb + 3 * 32);
#pragma unroll
        for (int g = 0; g < 4; g++) {
            f16x8 bf = *(const f16x8*)(wlds + (((wv * 8) + g) * 64 + lane) * 16);
            acc[g] = __builtin_amdgcn_mfma_f32_16x16x32_f16(afc, bf, acc[g], 0, 0, 0);
        }
        afc = afn;
        // S5: kt3 (LDS weights)
        afn = *(const f16x8*)(hb + 6 * 32);
#pragma unroll
        for (int g = 0; g < 4; g++) {
            f16x8 bf = *(const f16x8*)(wlds + (((wv * 8) + 4 + g) * 64 + lane) * 16);
            acc[g] = __builtin_amdgcn_mfma_f32_16x16x32_f16(afc, bf, acc[g], 0, 0, 0);
        }
        afc = afn;
        // S6: kt6 (bank A, refilled at S0 ~6 sections ago); refill A <- next step's kt4
        afn = *(const f16x8*)(hb + 7 * 32);
#pragma unroll
        for (int g = 0; g < 4; g++) {
            acc[g] = __builtin_amdgcn_mfma_f32_16x16x32_f16(afc, as_f16x8(sbufA[g]), acc[g], 0, 0, 0);
            sbufA[g] = *(const uint4*)(wbase + (size_t)g * 65536 + 4 * 32);
        }
        afc = afn;
        // S7: kt7 (bank B); refill B <- next step's kt5 (in flight across barrier)
#pragma unroll
        for (int g = 0; g < 4; g++) {
            acc[g] = __builtin_amdgcn_mfma_f32_16x16x32_f16(afc, as_f16x8(sbufB[g]), acc[g], 0, 0, 0);
            sbufB[g] = *(const uint4*)(wbase + (size_t)g * 65536 + 5 * 32);
        }
        // elementwise (in-register), write ys and next h; all loop loads precede stores
        unsigned short* hn = hbuf + ((t + 1) & 1) * HB_HALF;
#pragma unroll
        for (int r = 0; r < 4; r++) {
            float ig = sigmoid_fast(acc[0][r]);
            float fg = sigmoid_fast(acc[1][r]);
            float gg = tanh_fast(acc[2][r]);
            float og = sigmoid_fast(acc[3][r]);
            float cn = fg * creg[r] + ig * gg;
            creg[r] = cn;
            float hv = og * tanh_fast(cn);
            hn[(q * 4 + r) * HB_STRIDE + (wv << 4) + l15] = f2h(hv);
            outp[(size_t)r * T * 256] = hv;
        }
        outp += 256;
        lds_barrier();
    }
}

extern "C" void kernel_launch(void* const* d_in, const int* in_sizes, int n_in,
                              void* d_out, int out_size, void* d_ws, size_t ws_size,
                              hipStream_t stream) {
    const float* h   = (const float*)d_in[0];
    const float* c   = (const float*)d_in[1];
    const int*   seqp= (const int*)d_in[2];
    const float* iWh = (const float*)d_in[3];
    const float* ibh = (const float*)d_in[4];
    const float* iWc = (const float*)d_in[5];
    const float* ibc = (const float*)d_in[6];
    const float* Wih = (const float*)d_in[7];
    const float* Whh = (const float*)d_in[8];
    const float* bih = (const float*)d_in[9];
    const float* bhh = (const float*)d_in[10];
    float* out = (float*)d_out;
    unsigned char* ws = (unsigned char*)d_ws;

    // workspace layout (16B-aligned)
    unsigned short* hc_h  = (unsigned short*)(ws + 0);        // [1024,1024] fp16 = 2 MB
    unsigned short* iWh_h = (unsigned short*)(ws + 2097152);  // [256,1024]
    unsigned short* iWc_h = (unsigned short*)(ws + 2621440);  // [256,1024]
    unsigned short* Wih_h = (unsigned short*)(ws + 3145728);  // [1024,512]
    unsigned short* Whh_h = (unsigned short*)(ws + 4194304);  // [1024,256]
    float* h0  = (float*)(ws + 4718592);                       // [1024,256]
    float* c0  = (float*)(ws + 5767168);                       // [1024,256]
    float* xpT = (float*)(ws + 6815744);                       // [1024 gatecols,1024 rows]

    // fp16 conversions: all 6 tensors in one dispatch
    convert_all<<<2304, 256, 0, stream>>>(h, c, iWh, iWc, Wih, Whh,
                                          hc_h, iWh_h, iWc_h, Wih_h, Whh_h);

    // init states (fused pair) + transposed x_proj:
    // xpT[gatecol, batch] = Wih[gatecol,:] . h[batch,:] + bih[gatecol] + bhh[gatecol]
    gemm_init<<<dim3(16, 4, 2), 256, 0, stream>>>(hc_h, iWh_h, iWc_h, h0, c0, ibh, ibc);
    gemm_bt<<<dim3(16, 16), 256, 0, stream>>>(Wih_h, hc_h, xpT, bih, bhh,
                                              512, 512, 1024, 1024, 0, 1);

    // recurrence
    lstm_rec<<<64, 1024, 0, stream>>>(Whh_h, xpT, h0, c0, seqp, out);
}

// Round 5
// 1298.188 us; speedup vs baseline: 1.2513x; 1.2209x over previous
//
#include <hip/hip_runtime.h>
#include <stdint.h>

typedef __attribute__((ext_vector_type(4))) float f32x4;
typedef __attribute__((ext_vector_type(8))) _Float16 f16x8;

static __device__ __forceinline__ unsigned short f2h(float f) {
    union { _Float16 h; unsigned short u; } v;
    v.h = (_Float16)f;                      // v_cvt_f16_f32, RNE
    return v.u;
}
static __device__ __forceinline__ f16x8 as_f16x8(uint4 v) {
    union { uint4 u; f16x8 s; } x; x.u = v; return x.s;
}
static __device__ __forceinline__ float sigmoid_fast(float x) {
    return __builtin_amdgcn_rcpf(1.0f + __builtin_amdgcn_exp2f(-1.4426950408889634f * x));
}
static __device__ __forceinline__ float tanh_fast(float x) {
    return 1.0f - 2.0f * __builtin_amdgcn_rcpf(1.0f + __builtin_amdgcn_exp2f(2.8853900817779268f * x));
}
// barrier that waits only LDS (lgkmcnt(0)), NOT vmcnt — global stores keep retiring async.
static __device__ __forceinline__ void lds_barrier() {
    __builtin_amdgcn_s_waitcnt(0xc07f);
    __builtin_amdgcn_s_barrier();
}

// ---------- fused fp32 -> fp16 conversion for all 6 tensors (1 dispatch) ----------
__global__ __launch_bounds__(256) void convert_all(
    const float* __restrict__ h, const float* __restrict__ c,
    const float* __restrict__ iWh, const float* __restrict__ iWc,
    const float* __restrict__ Wih, const float* __restrict__ Whh,
    unsigned short* __restrict__ hc_h, unsigned short* __restrict__ iWh_h,
    unsigned short* __restrict__ iWc_h, unsigned short* __restrict__ Wih_h,
    unsigned short* __restrict__ Whh_h) {
    int i = blockIdx.x * 256 + threadIdx.x;      // float4 index, total 589824
    const float* src; unsigned short* dst;
    if (i < 131072) {            // h -> hc[:, 0:512]
        int base = i * 4, r = base >> 9, cc = base & 511;
        src = h + base; dst = hc_h + r * 1024 + cc;
    } else if (i < 262144) {     // c -> hc[:, 512:1024]
        int j = i - 131072; int base = j * 4, r = base >> 9, cc = base & 511;
        src = c + base; dst = hc_h + r * 1024 + 512 + cc;
    } else if (i < 327680) { int j = i - 262144; src = iWh + j * 4; dst = iWh_h + j * 4; }
    else if (i < 393216)   { int j = i - 327680; src = iWc + j * 4; dst = iWc_h + j * 4; }
    else if (i < 524288)   { int j = i - 393216; src = Wih + j * 4; dst = Wih_h + j * 4; }
    else                   { int j = i - 524288; src = Whh + j * 4; dst = Whh_h + j * 4; }
    float4 v = *(const float4*)src;
    dst[0] = f2h(v.x); dst[1] = f2h(v.y); dst[2] = f2h(v.z); dst[3] = f2h(v.w);
}

// ---------- generic C[M,N] = A[M,lda] @ W[N,ldw(:K)]^T + bias (+ELU), fp16 in / fp32 out ----
__global__ __launch_bounds__(256) void gemm_bt(
    const unsigned short* __restrict__ A, const unsigned short* __restrict__ W,
    float* __restrict__ C, const float* __restrict__ b1, const float* __restrict__ b2,
    int K, int lda, int ldw, int N, int do_elu, int bias_row) {
    __shared__ unsigned short As[64][40];
    __shared__ unsigned short Bs[64][40];
    int tid = threadIdx.x;
    int lane = tid & 63, wv = tid >> 6;
    int q = lane >> 4, l15 = lane & 15;
    int Mbase = blockIdx.x * 64, Nbase = blockIdx.y * 64;
    int ldrow = tid >> 2, seg = tid & 3;
    const unsigned short* Ap = A + (size_t)(Mbase + ldrow) * lda + seg * 8;
    const unsigned short* Wp = W + (size_t)(Nbase + ldrow) * ldw + seg * 8;
    f32x4 acc[4] = {};
    for (int k0 = 0; k0 < K; k0 += 32) {
        uint4 av = *(const uint4*)(Ap + k0);
        uint4 wvv = *(const uint4*)(Wp + k0);
        __syncthreads();
        *(uint4*)(&As[ldrow][seg * 8]) = av;
        *(uint4*)(&Bs[ldrow][seg * 8]) = wvv;
        __syncthreads();
        f16x8 af = *(const f16x8*)(&As[wv * 16 + l15][q * 8]);
#pragma unroll
        for (int nt = 0; nt < 4; nt++) {
            f16x8 bf = *(const f16x8*)(&Bs[nt * 16 + l15][q * 8]);
            acc[nt] = __builtin_amdgcn_mfma_f32_16x16x32_f16(af, bf, acc[nt], 0, 0, 0);
        }
    }
#pragma unroll
    for (int nt = 0; nt < 4; nt++) {
        int col = Nbase + nt * 16 + l15;
        float bcol = bias_row ? 0.0f : (b1[col] + (b2 ? b2[col] : 0.0f));
#pragma unroll
        for (int r = 0; r < 4; r++) {
            int row = Mbase + wv * 16 + q * 4 + r;
            float bias = bias_row ? (b1[row] + (b2 ? b2[row] : 0.0f)) : bcol;
            float v = acc[nt][r] + bias;
            if (do_elu) v = v > 0.0f ? v : (__builtin_amdgcn_exp2f(1.4426950408889634f * v) - 1.0f);
            C[(size_t)row * N + col] = v;
        }
    }
}

// ---------- fused init-state GEMMs (h0 and c0 via blockIdx.z), K=1024, N=256, ELU ----------
__global__ __launch_bounds__(256) void gemm_init(
    const unsigned short* __restrict__ A,
    const unsigned short* __restrict__ W0, const unsigned short* __restrict__ W1,
    float* __restrict__ C0, float* __restrict__ C1,
    const float* __restrict__ bias0, const float* __restrict__ bias1) {
    const unsigned short* W = blockIdx.z ? W1 : W0;
    float* C = blockIdx.z ? C1 : C0;
    const float* bias = blockIdx.z ? bias1 : bias0;
    __shared__ unsigned short As[64][40];
    __shared__ unsigned short Bs[64][40];
    int tid = threadIdx.x;
    int lane = tid & 63, wv = tid >> 6;
    int q = lane >> 4, l15 = lane & 15;
    int Mbase = blockIdx.x * 64, Nbase = blockIdx.y * 64;
    int ldrow = tid >> 2, seg = tid & 3;
    const unsigned short* Ap = A + (size_t)(Mbase + ldrow) * 1024 + seg * 8;
    const unsigned short* Wp = W + (size_t)(Nbase + ldrow) * 1024 + seg * 8;
    f32x4 acc[4] = {};
    for (int k0 = 0; k0 < 1024; k0 += 32) {
        uint4 av = *(const uint4*)(Ap + k0);
        uint4 wvv = *(const uint4*)(Wp + k0);
        __syncthreads();
        *(uint4*)(&As[ldrow][seg * 8]) = av;
        *(uint4*)(&Bs[ldrow][seg * 8]) = wvv;
        __syncthreads();
        f16x8 af = *(const f16x8*)(&As[wv * 16 + l15][q * 8]);
#pragma unroll
        for (int nt = 0; nt < 4; nt++) {
            f16x8 bf = *(const f16x8*)(&Bs[nt * 16 + l15][q * 8]);
            acc[nt] = __builtin_amdgcn_mfma_f32_16x16x32_f16(af, bf, acc[nt], 0, 0, 0);
        }
    }
#pragma unroll
    for (int nt = 0; nt < 4; nt++) {
        int col = Nbase + nt * 16 + l15;
        float b = bias[col];
#pragma unroll
        for (int r = 0; r < 4; r++) {
            int row = Mbase + wv * 16 + q * 4 + r;
            float v = acc[nt][r] + b;
            v = v > 0.0f ? v : (__builtin_amdgcn_exp2f(1.4426950408889634f * v) - 1.0f);
            C[(size_t)row * 256 + col] = v;
        }
    }
}

// ---------- persistent recurrent kernel: 64 blocks x 512 thr, 16 rows/block ----------
// FULL Whh residency per CU (zero per-step weight traffic — r0-r3 were bound at ~10600
// cyc/step streaming 256 KB/CU/step from L2; time invariant across 4 scheduling variants).
// 8 waves x 256 regs (launch_bounds(512,2); 156 KB LDS forces 1 block/CU, 2 waves/SIMD):
//   wave wv owns latent cols [32wv,32wv+32) x 4 gates = 64 Whh frags (1 KB each):
//   47 frags in regs (188), 17 in LDS (139 KB; LDS-capped). M=16: no padding, no clamps.
// acc re-init per step: 8 dwordx4 loads from xpT issued BEFORE the out-stores (vmcnt is a
// FIFO — r1 issued them after the stores and every step waited on store drain) and pinned
// by sched_barrier(0); the wait lands at the next step's first MFMA, ~600+ cyc later.
// In-loop live set: wreg 188 + acc 32 + creg 8 + hv 8 + addr ~10 = ~246 <= 256.
#define HB_STRIDE 264                    // fp16 elems per h row (33x16B: 2-way-free af reads)
#define HB_HALF   (16 * HB_STRIDE)      // one h buffer, elems
#define WLDS_OFF  (2 * HB_HALF * 2)     // bytes: 16896
#define WFRAGS    17                     // LDS weight frags per wave (1 KB each)
#define LSTM_LDS_BYTES (WLDS_OFF + 8 * WFRAGS * 1024)   // 156160 <= 163840

__global__ __launch_bounds__(512, 2) void lstm_rec(
    const unsigned short* __restrict__ Whh,   // [1024,256] fp16
    const float* __restrict__ xpT,            // [1024 gatecols, 1024 rows] fp32
    const float* __restrict__ h0,             // [1024,256]
    const float* __restrict__ c0,             // [1024,256]
    const int* __restrict__ seq_len,
    float* __restrict__ out)                  // [1024, T, 256]
{
    __shared__ uint4 smem4[LSTM_LDS_BYTES / 16];
    unsigned short* hbuf = (unsigned short*)smem4;           // [2][16][HB_STRIDE]
    unsigned char* wlds = (unsigned char*)smem4 + WLDS_OFF;  // 8 waves * 17 frags * 1 KB
    const int tid = threadIdx.x;
    const int lane = tid & 63, wv = tid >> 6;   // wv 0..7
    const int q = lane >> 4, l15 = lane & 15;
    const int T = *seq_len;
    const int rowbase = blockIdx.x * 16;

    {   // h0 -> hbuf[0] rows 0..15 as fp16 (512 thr * 8 elems = 16*256 exactly)
        int e = tid * 8;
        int r = e >> 8, cc = e & 255;
        const float* s = h0 + (size_t)(rowbase + r) * 256 + cc;
        float4 v0 = *(const float4*)s;
        float4 v1 = *(const float4*)(s + 4);
        unsigned short* d = hbuf + r * HB_STRIDE + cc;
        d[0] = f2h(v0.x); d[1] = f2h(v0.y); d[2] = f2h(v0.z); d[3] = f2h(v0.w);
        d[4] = f2h(v1.x); d[5] = f2h(v1.y); d[6] = f2h(v1.z); d[7] = f2h(v1.w);
    }

    // weight fragment (kt,g,ct): elem = g*65536 + wv*8192 + ct*4096 + l15*256 + kt*32 + q*8
    const unsigned short* wb = Whh + wv * 8192 + l15 * 256 + q * 8;

    // 47 frags -> registers (frag id fi = kt*8 + g*2 + ct, kt 0..5; fi==47 lives in LDS)
    uint4 wreg[47];
#pragma unroll
    for (int kt = 0; kt < 6; kt++)
#pragma unroll
        for (int g = 0; g < 4; g++)
#pragma unroll
            for (int ct = 0; ct < 2; ct++) {
                int fi = kt * 8 + g * 2 + ct;
                if (fi < 47)
                    wreg[fi] = *(const uint4*)(wb + (size_t)g * 65536 + ct * 4096 + kt * 32);
            }

    // 17 frags -> LDS: slots 0-7 = kt6, 8-15 = kt7, 16 = (kt5,g3,ct1); lane-linear 16B
    unsigned char* wlp = wlds + wv * (WFRAGS * 1024) + lane * 16;
#pragma unroll
    for (int fi = 0; fi < WFRAGS; fi++) {
        int kt = (fi < 8) ? 6 : (fi < 16 ? 7 : 5);
        int p  = (fi < 16) ? (fi & 7) : 7;
        int g = p >> 1, ct = p & 1;
        uint4 v = *(const uint4*)(wb + (size_t)g * 65536 + ct * 4096 + kt * 32);
        *(uint4*)(wlp + fi * 1024) = v;
    }

    // c0 -> 8 f32 regs
    float creg[8];
#pragma unroll
    for (int ct = 0; ct < 2; ct++)
#pragma unroll
        for (int r = 0; r < 4; r++)
            creg[ct * 4 + r] = c0[(size_t)(rowbase + q * 4 + r) * 256 + wv * 32 + ct * 16 + l15];

    // x-proj base: acc[p] loads from xpb + (p>>1)*262144 + (p&1)*16384 each step
    const float* xpb = xpT + (size_t)(wv * 32 + l15) * 1024 + rowbase + (q << 2);
    f32x4 acc[8];
#pragma unroll
    for (int p = 0; p < 8; p++)
        acc[p] = *(const f32x4*)(xpb + (size_t)(p >> 1) * 262144 + (p & 1) * 16384);

    float* outp = out + ((size_t)(rowbase + q * 4) * T) * 256 + wv * 32 + l15;

    __syncthreads();

    for (int t = 0; t < T; t++) {
        const unsigned short* hb = hbuf + (t & 1) * HB_HALF + l15 * HB_STRIDE + q * 8;
        // K loop: all weights resident (regs or LDS); 1 af read feeds 8 MFMAs
#pragma unroll
        for (int kt = 0; kt < 8; kt++) {
            f16x8 af = *(const f16x8*)(hb + kt * 32);
#pragma unroll
            for (int p = 0; p < 8; p++) {
                f16x8 bf;
                if (kt < 6 && !(kt == 5 && p == 7))
                    bf = as_f16x8(wreg[kt * 8 + p]);
                else if (kt == 6)
                    bf = *(const f16x8*)(wlp + p * 1024);
                else if (kt == 7)
                    bf = *(const f16x8*)(wlp + (8 + p) * 1024);
                else // kt==5, p==7
                    bf = *(const f16x8*)(wlp + 16 * 1024);
                acc[p] = __builtin_amdgcn_mfma_f32_16x16x32_f16(af, bf, acc[p], 0, 0, 0);
            }
        }
        // elementwise: consume acc into hv (acc dead after this loop)
        float hv[8];
#pragma unroll
        for (int ct = 0; ct < 2; ct++)
#pragma unroll
            for (int r = 0; r < 4; r++) {
                float ig = sigmoid_fast(acc[0 + ct][r]);
                float fg = sigmoid_fast(acc[2 + ct][r]);
                float gg = tanh_fast(acc[4 + ct][r]);
                float og = sigmoid_fast(acc[6 + ct][r]);
                float cn = fg * creg[ct * 4 + r] + ig * gg;
                creg[ct * 4 + r] = cn;
                hv[ct * 4 + r] = og * tanh_fast(cn);
            }
        // prefetch next step's acc NOW (before any store enters the vmcnt FIFO)
#pragma unroll
        for (int p = 0; p < 8; p++)
            acc[p] = *(const f32x4*)(xpb + (size_t)(p >> 1) * 262144 + (p & 1) * 16384);
        __builtin_amdgcn_sched_barrier(0);   // keep loads issued ahead of the stores below
        // write next h (LDS) and ys (global)
        unsigned short* hn = hbuf + ((t + 1) & 1) * HB_HALF + (q * 4) * HB_STRIDE + wv * 32 + l15;
#pragma unroll
        for (int ct = 0; ct < 2; ct++)
#pragma unroll
            for (int r = 0; r < 4; r++) {
                hn[r * HB_STRIDE + ct * 16] = f2h(hv[ct * 4 + r]);
                outp[(size_t)r * T * 256 + ct * 16] = hv[ct * 4 + r];
            }
        outp += 256;
        lds_barrier();
    }
}

extern "C" void kernel_launch(void* const* d_in, const int* in_sizes, int n_in,
                              void* d_out, int out_size, void* d_ws, size_t ws_size,
                              hipStream_t stream) {
    const float* h   = (const float*)d_in[0];
    const float* c   = (const float*)d_in[1];
    const int*   seqp= (const int*)d_in[2];
    const float* iWh = (const float*)d_in[3];
    const float* ibh = (const float*)d_in[4];
    const float* iWc = (const float*)d_in[5];
    const float* ibc = (const float*)d_in[6];
    const float* Wih = (const float*)d_in[7];
    const float* Whh = (const float*)d_in[8];
    const float* bih = (const float*)d_in[9];
    const float* bhh = (const float*)d_in[10];
    float* out = (float*)d_out;
    unsigned char* ws = (unsigned char*)d_ws;

    // workspace layout (16B-aligned)
    unsigned short* hc_h  = (unsigned short*)(ws + 0);        // [1024,1024] fp16 = 2 MB
    unsigned short* iWh_h = (unsigned short*)(ws + 2097152);  // [256,1024]
    unsigned short* iWc_h = (unsigned short*)(ws + 2621440);  // [256,1024]
    unsigned short* Wih_h = (unsigned short*)(ws + 3145728);  // [1024,512]
    unsigned short* Whh_h = (unsigned short*)(ws + 4194304);  // [1024,256]
    float* h0  = (float*)(ws + 4718592);                       // [1024,256]
    float* c0  = (float*)(ws + 5767168);                       // [1024,256]
    float* xpT = (float*)(ws + 6815744);                       // [1024 gatecols,1024 rows]

    // fp16 conversions: all 6 tensors in one dispatch
    convert_all<<<2304, 256, 0, stream>>>(h, c, iWh, iWc, Wih, Whh,
                                          hc_h, iWh_h, iWc_h, Wih_h, Whh_h);

    // init states (fused pair) + transposed x_proj:
    // xpT[gatecol, batch] = Wih[gatecol,:] . h[batch,:] + bih[gatecol] + bhh[gatecol]
    gemm_init<<<dim3(16, 4, 2), 256, 0, stream>>>(hc_h, iWh_h, iWc_h, h0, c0, ibh, ibc);
    gemm_bt<<<dim3(16, 16), 256, 0, stream>>>(Wih_h, hc_h, xpT, bih, bhh,
                                              512, 512, 1024, 1024, 0, 1);

    // recurrence: 64 blocks x 512 threads, fully weight-resident, M=16 (no padding)
    lstm_rec<<<64, 512, 0, stream>>>(Whh_h, xpT, h0, c0, seqp, out);
}